// Round 1
// baseline (143.658 us; speedup 1.0000x reference)
//
#include <hip/hip_runtime.h>

#define THREADS 256
#define IPB 4   // images per block; grid = batch/4 = 2048

typedef _Float16 f16;
typedef _Float16 f16x2 __attribute__((ext_vector_type(2)));
typedef _Float16 f16x8 __attribute__((ext_vector_type(8)));
typedef float f32x4 __attribute__((ext_vector_type(4)));
typedef float f32x16 __attribute__((ext_vector_type(16)));
typedef unsigned int uint;

__device__ __forceinline__ f16x2 pkrtz(float a, float b) {
    return __builtin_bit_cast(f16x2, __builtin_amdgcn_cvt_pkrtz(a, b));
}
template<int CTRL>
__device__ __forceinline__ float dppmax(float v) {   // fmax with DPP-shuffled lane
    const int i = __builtin_bit_cast(int, v);
    const int s = __builtin_amdgcn_update_dpp(i, i, CTRL, 0xF, 0xF, true);
    return fmaxf(v, __builtin_bit_cast(float, s));
}

// p1 layout: [img][iy 12][ix 12][ic 16] f16. Row stride 400B; final row unpadded
// so img stride = 11*400+384 = 4784B. ic 10..15 zeros (K-pad).
#define P1_ROW 400
#define P1_IMG 4784
// LDS map (single block of 32128 B):
//   [0, 19136)      p1c
//   [19136, 32128)  pairs: f16x2 [img][row 28][col 29] — word stride 29 (odd,
//                   low bank conflict), img stride 812 words = 3248 B
//   after conv1, pairs region is dead and is aliased by:
//   [19136, 21760)  p2h  (4 * 328 f16)
//   [21760, 22592)  h1   (4 * 52 f32)
#define PAIRS_OFF 19136
#define PAIR_IMG 812
#define PAIR_ROW 29
#define SMEM_BYTES 32128

// d_ws layout: [0)      w1pk   250 x uint (dup f16 pairs)
//              [1024)   w2af   1000 x f16x8  (conv2 A-frags [s][oc*2+hK])
//              [17408)  wl1pk  2560 x f16x8  (fc1 A-frags [tile][s][lane])
__global__ void pack_weights(const float* __restrict__ w1,
                             const float* __restrict__ w2,
                             const float* __restrict__ wl1,
                             unsigned char* __restrict__ ws) {
    uint* w1pk  = (uint*)ws;
    f16x8* w2af = (f16x8*)(ws + 1024);
    f16x8* wl1pk = (f16x8*)(ws + 17408);
    const int gid = blockIdx.x * blockDim.x + threadIdx.x;
    const int gsz = gridDim.x * blockDim.x;
    for (int i = gid; i < 250; i += gsz) {
        const unsigned short u =
            __builtin_bit_cast(unsigned short, (f16)w1[i]);
        w1pk[i] = (uint)u | ((uint)u << 16);
    }
    for (int e = gid; e < 1000; e += gsz) {          // conv2 A-frags
        const int s = e / 40, r = e - s * 40;
        const int oc = r >> 1, h = r & 1;
        f16x8 a;
        #pragma unroll
        for (int j = 0; j < 8; ++j) {
            const int ic = h * 8 + j;
            a[j] = (f16)(ic < 10 ? w2[(oc * 10 + ic) * 25 + s] : 0.f);
        }
        w2af[e] = a;
    }
    for (int e = gid; e < 2560; e += gsz) {          // fc1 A-frags
        const int tile = e / 640, rem = e % 640;
        const int s = rem / 64, lane = rem % 64;
        const int m = lane & 15, quad = lane >> 4;
        const int hh = tile * 16 + m;
        f16x8 a;
        #pragma unroll
        for (int j = 0; j < 8; ++j)
            a[j] = (f16)(hh < 50 ? wl1[hh * 320 + s * 32 + quad * 8 + j] : 0.f);
        wl1pk[e] = a;
    }
}

// LDS 32128 B -> 5 blocks/CU; launch_bounds(256,5) -> VGPR cap 96 (was 80).
__global__ __launch_bounds__(THREADS, 5)
void lenet_one(const float* __restrict__ x,
               const unsigned char* __restrict__ ws, const float* __restrict__ b1,
               const float* __restrict__ b2,
               const float* __restrict__ bl1,
               const float* __restrict__ wl2, const float* __restrict__ bl2,
               float* __restrict__ out, int batch)
{
    __shared__ __align__(16) unsigned char smem[SMEM_BYTES];
    unsigned char* p1c = smem;
    f16x2* prl = (f16x2*)(smem + PAIRS_OFF);
    f16*   p2h = (f16*)(smem + PAIRS_OFF);            // aliases pairs (dead)
    float* h1  = (float*)(smem + PAIRS_OFF + 2624);   // aliases pairs (dead)

    const uint*  w1pk  = (const uint*)ws;
    const f16x8* w2af  = (const f16x8*)(ws + 1024);
    const f16x8* wl1pk = (const f16x8*)(ws + 17408);

    const int tid = threadIdx.x;
    const int lane = tid & 63;
    const int wv_ = tid >> 6;                 // wave id 0..3
    const int cM = lane & 31, hK = lane >> 5; // conv2 MFMA: row m=cM, K-half hK
    const int img = tid & 3;

    // ---------- phase 0: stage x as f16 pairs in LDS (coalesced, dense) ------
    // pairs[img][row][c] = pkrtz(x[row*28+c], x[row*28+c+1]); c==27 -> zero pad
    for (int e = tid; e < 3136; e += THREADS) {
        const int c = e % 28, t = e / 28;
        const int row = t % 28, im2 = t / 28;
        const int ig = min(blockIdx.x * IPB + im2, batch - 1);
        f16x2 pv = {(f16)0.f, (f16)0.f};
        if (c < 27) {
            const float* xp = x + (size_t)ig * 784 + row * 28 + c;
            pv = pkrtz(xp[0], xp[1]);
        }
        prl[im2 * PAIR_IMG + row * PAIR_ROW + c] = pv;
    }
    __syncthreads();

    // ---------- conv1 (1->10ch) packed f16 + bias + relu + pool --------------
    // window pairs come from LDS via ds_read_b32 with immediate offsets
    {
        const int grp = tid >> 2;                 // 0..63 position groups
        const f16x2* pbase = prl + img * PAIR_IMG;
        for (int pq = grp; pq < 144; pq += 64) {
            const int py = pq / 12, px = pq - py * 12;
            const f16x2* pb = pbase + (2 * py) * PAIR_ROW + 2 * px;
            f16x2 pr[30];                         // 6 rows x 5 shifted pairs
            #pragma unroll
            for (int r = 0; r < 6; ++r)
                #pragma unroll
                for (int cc = 0; cc < 5; ++cc)
                    pr[r * 5 + cc] = pb[r * PAIR_ROW + cc];
            f16 ch[10];
            #pragma unroll
            for (int c = 0; c < 10; ++c) {
                f16x2 accT = {(f16)0.f, (f16)0.f};
                f16x2 accB = {(f16)0.f, (f16)0.f};
                #pragma unroll
                for (int ky = 0; ky < 5; ++ky)
                    #pragma unroll
                    for (int kx = 0; kx < 5; ++kx) {
                        const uint wp = w1pk[c * 25 + ky * 5 + kx]; // sgpr
                        const f16x2 wv = __builtin_bit_cast(f16x2, wp);
                        accT += pr[ky * 5 + kx] * wv;        // v_pk_fma_f16
                        accB += pr[(ky + 1) * 5 + kx] * wv;
                    }
                const f16x2 qm = __builtin_elementwise_max(accT, accB); // pk_max
                const float q = fmaxf((float)qm[0], (float)qm[1]);
                ch[c] = (f16)fmaxf(q + b1[c], 0.f);
            }
            f16x8 v0, v1;
            #pragma unroll
            for (int j = 0; j < 8; ++j) v0[j] = ch[j];
            v1[0] = ch[8]; v1[1] = ch[9];
            #pragma unroll
            for (int j = 2; j < 8; ++j) v1[j] = (f16)0.f;   // K-pad zeros
            unsigned char* dst = p1c + img * P1_IMG + py * P1_ROW + px * 32;
            *(f16x8*)(dst)      = v0;
            *(f16x8*)(dst + 16) = v1;
        }
    }
    __syncthreads();

    // ---------- conv2 via mfma_f32_32x32x16_f16; A-frags from global ----------
    {
        const int cy = cM >> 3, cx = cM & 7;
        const int afoff = (cM < 20 ? cM : 19) * 2 + hK;
        int bb[2];
        #pragma unroll
        for (int q = 0; q < 2; ++q) {
            const int t = wv_ * 2 + q, im = t >> 1, h2 = t & 1;
            bb[q] = im * P1_IMG + (4 * h2 + cy) * P1_ROW + cx * 32 + hK * 16;
        }
        f32x16 acc[2];
        #pragma unroll
        for (int q = 0; q < 2; ++q)
            #pragma unroll
            for (int r = 0; r < 16; ++r) acc[q][r] = 0.f;
        #pragma unroll 1
        for (int ky = 0; ky < 5; ++ky) {
            #pragma unroll
            for (int kx = 0; kx < 5; ++kx) {
                const f16x8 a = w2af[(ky * 5 + kx) * 40 + afoff];
                #pragma unroll
                for (int q = 0; q < 2; ++q) {
                    const f16x8 b =
                        *(const f16x8*)(p1c + bb[q] + ky * P1_ROW + kx * 32);
                    acc[q] = __builtin_amdgcn_mfma_f32_32x32x16_f16(a, b, acc[q],
                                                                    0, 0, 0);
                }
            }
        }
        // epilogue: pool via DPP (xor1 = quad_perm(1,0,3,2)=0xB1; xor8 = row_ror:8)
        #pragma unroll
        for (int q = 0; q < 2; ++q) {
            const int t = wv_ * 2 + q, im = t >> 1, h2 = t & 1;
            #pragma unroll
            for (int r = 0; r < 16; ++r) {
                const int m = (r & 3) + 8 * (r >> 2) + 4 * hK;
                float v = acc[q][r];
                v = dppmax<0xB1>(v);
                v = dppmax<0x128>(v);
                if (m < 20 && (lane & 9) == 0) {
                    const int py = 2 * h2 + (cM >> 4), px = cx >> 1;
                    p2h[im * 328 + m * 16 + py * 4 + px] =
                        (f16)fmaxf(v + b2[m], 0.f);
                }
            }
        }
    }
    __syncthreads();

    // ---------- fc1 via mfma_f32_16x16x32_f16: M=h tile/wave, N=img, K=320 ----
    {
        const int n = lane & 15, quad = lane >> 4;
        f32x4 facc = {0.f, 0.f, 0.f, 0.f};
        #pragma unroll 1
        for (int s = 0; s < 10; ++s) {
            const f16x8 a = wl1pk[(wv_ * 10 + s) * 64 + lane];  // coalesced b128
            f16x8 b = {};
            if (n < IPB)
                b = *(const f16x8*)(p2h + n * 328 + s * 32 + quad * 8);
            facc = __builtin_amdgcn_mfma_f32_16x16x32_f16(a, b, facc, 0, 0, 0);
        }
        if (n < IPB) {
            #pragma unroll
            for (int r = 0; r < 4; ++r) {
                const int h = wv_ * 16 + quad * 4 + r;
                if (h < 50)
                    h1[n * 52 + h] = fmaxf(facc[r] + bl1[h], 0.f);
            }
        }
    }
    __syncthreads();

    // ---------- fc2: 50->10 ---------------------------------------------------
    if (tid < IPB * 10) {
        const int im = tid / 10, o = tid % 10;
        const int imgo = min(blockIdx.x * IPB + im, batch - 1);
        float a = bl2[o];
        #pragma unroll
        for (int h = 0; h < 50; ++h)
            a += h1[im * 52 + h] * wl2[o * 50 + h];
        out[(size_t)imgo * 10 + o] = a;          // coalesced
    }
}

extern "C" void kernel_launch(void* const* d_in, const int* in_sizes, int n_in,
                              void* d_out, int out_size, void* d_ws, size_t ws_size,
                              hipStream_t stream) {
    const float* x   = (const float*)d_in[0];
    const float* w1  = (const float*)d_in[1];
    const float* b1  = (const float*)d_in[2];
    const float* w2  = (const float*)d_in[3];
    const float* b2  = (const float*)d_in[4];
    const float* wl1 = (const float*)d_in[5];
    const float* bl1 = (const float*)d_in[6];
    const float* wl2 = (const float*)d_in[7];
    const float* bl2 = (const float*)d_in[8];
    float* out = (float*)d_out;
    unsigned char* ws = (unsigned char*)d_ws;   // 58 KB of packed weights

    const int batch = in_sizes[0] / 784;  // 8192
    pack_weights<<<16, 256, 0, stream>>>(w1, w2, wl1, ws);
    const int grid = (batch + IPB - 1) / IPB;
    lenet_one<<<grid, THREADS, 0, stream>>>(x, ws, b1, b2, bl1, wl2, bl2,
                                            out, batch);
}

// Round 2
// 135.159 us; speedup vs baseline: 1.0629x; 1.0629x over previous
//
#include <hip/hip_runtime.h>

#define THREADS 256
#define IPB 4   // images per block; grid = batch/4 = 2048

typedef _Float16 f16;
typedef _Float16 f16x2 __attribute__((ext_vector_type(2)));
typedef _Float16 f16x8 __attribute__((ext_vector_type(8)));
typedef float f32x4 __attribute__((ext_vector_type(4)));
typedef float f32x16 __attribute__((ext_vector_type(16)));
typedef unsigned int uint;

__device__ __forceinline__ f16x2 pkrtz(float a, float b) {
    return __builtin_bit_cast(f16x2, __builtin_amdgcn_cvt_pkrtz(a, b));
}
template<int CTRL>
__device__ __forceinline__ float dppmax(float v) {   // fmax with DPP-shuffled lane
    const int i = __builtin_bit_cast(int, v);
    const int s = __builtin_amdgcn_update_dpp(i, i, CTRL, 0xF, 0xF, true);
    return fmaxf(v, __builtin_bit_cast(float, s));
}

// p1 layout: [img][iy 12][ix 12][ic 16] f16. Row stride 400B; final row unpadded
// so img stride = 11*400+384 = 4784B. ic 10..15 zeros (K-pad).
#define P1_ROW 400
#define P1_IMG 4784
// LDS: single 19136 B block. p2h/h1 ALIAS p1c (p1c is dead once conv2's MFMA
// loop finishes; an extra barrier separates last p1c read from first p2h
// write). 19136 B -> 8 blocks/CU (was 7 at 23 KB): grid 2048 = 8/CU runs as
// ONE resident round, no straggler tail.
#define SMEM_BYTES 19136

// d_ws layout: [0)      w1pk   250 x uint (dup f16 pairs)
//              [1024)   w2af   1000 x f16x8  (conv2 A-frags [s][oc*2+hK])
//              [17408)  wl1pk  2560 x f16x8  (fc1 A-frags [tile][s][lane])
__global__ void pack_weights(const float* __restrict__ w1,
                             const float* __restrict__ w2,
                             const float* __restrict__ wl1,
                             unsigned char* __restrict__ ws) {
    uint* w1pk  = (uint*)ws;
    f16x8* w2af = (f16x8*)(ws + 1024);
    f16x8* wl1pk = (f16x8*)(ws + 17408);
    const int gid = blockIdx.x * blockDim.x + threadIdx.x;
    const int gsz = gridDim.x * blockDim.x;
    for (int i = gid; i < 250; i += gsz) {
        const unsigned short u =
            __builtin_bit_cast(unsigned short, (f16)w1[i]);
        w1pk[i] = (uint)u | ((uint)u << 16);
    }
    for (int e = gid; e < 1000; e += gsz) {          // conv2 A-frags
        const int s = e / 40, r = e - s * 40;
        const int oc = r >> 1, h = r & 1;
        f16x8 a;
        #pragma unroll
        for (int j = 0; j < 8; ++j) {
            const int ic = h * 8 + j;
            a[j] = (f16)(ic < 10 ? w2[(oc * 10 + ic) * 25 + s] : 0.f);
        }
        w2af[e] = a;
    }
    for (int e = gid; e < 2560; e += gsz) {          // fc1 A-frags
        const int tile = e / 640, rem = e % 640;
        const int s = rem / 64, lane = rem % 64;
        const int m = lane & 15, quad = lane >> 4;
        const int hh = tile * 16 + m;
        f16x8 a;
        #pragma unroll
        for (int j = 0; j < 8; ++j)
            a[j] = (f16)(hh < 50 ? wl1[hh * 320 + s * 32 + quad * 8 + j] : 0.f);
        wl1pk[e] = a;
    }
}

__global__ __launch_bounds__(THREADS, 8)
void lenet_one(const float* __restrict__ x,
               const unsigned char* __restrict__ ws, const float* __restrict__ b1,
               const float* __restrict__ b2,
               const float* __restrict__ bl1,
               const float* __restrict__ wl2, const float* __restrict__ bl2,
               float* __restrict__ out, int batch)
{
    __shared__ __align__(16) unsigned char p1c[SMEM_BYTES];
    f16*   p2h = (f16*)p1c;             // [img][k 320 pad 328], aliases p1c
    float* h1  = (float*)(p1c + 2624);  // [img][50 pad 52],     aliases p1c

    const uint*  w1pk  = (const uint*)ws;
    const f16x8* w2af  = (const f16x8*)(ws + 1024);
    const f16x8* wl1pk = (const f16x8*)(ws + 17408);

    const int tid = threadIdx.x;
    const int lane = tid & 63;
    const int wv_ = tid >> 6;                 // wave id 0..3
    const int cM = lane & 31, hK = lane >> 5; // conv2 MFMA: row m=cM, K-half hK
    const int img = tid & 3;
    const int imgg = min(blockIdx.x * IPB + img, batch - 1);

    // ---------- conv1 (1->10ch) packed f16 + bias + relu + pool ---------------
    {
        const int grp = tid >> 2;                 // 0..63 position groups
        const float* xim = x + (size_t)imgg * 784;
        for (int pq = grp; pq < 144; pq += 64) {
            const int py = pq / 12, px = pq % 12;
            const float* xb = xim + (2 * py) * 28 + 2 * px;
            float win[36];
            #pragma unroll
            for (int r = 0; r < 6; ++r)
                #pragma unroll
                for (int cc = 0; cc < 6; ++cc)
                    win[r * 6 + cc] = xb[r * 28 + cc];
            f16x2 pr[30];                         // shifted pairs, reused x10 ch
            #pragma unroll
            for (int r = 0; r < 6; ++r)
                #pragma unroll
                for (int cc = 0; cc < 5; ++cc)
                    pr[r * 5 + cc] = pkrtz(win[r * 6 + cc], win[r * 6 + cc + 1]);
            f16 ch[10];
            #pragma unroll
            for (int c = 0; c < 10; ++c) {
                f16x2 accT = {(f16)0.f, (f16)0.f};
                f16x2 accB = {(f16)0.f, (f16)0.f};
                #pragma unroll
                for (int ky = 0; ky < 5; ++ky)
                    #pragma unroll
                    for (int kx = 0; kx < 5; ++kx) {
                        const uint wp = w1pk[c * 25 + ky * 5 + kx]; // sgpr
                        const f16x2 wv = __builtin_bit_cast(f16x2, wp);
                        accT += pr[ky * 5 + kx] * wv;        // v_pk_fma_f16
                        accB += pr[(ky + 1) * 5 + kx] * wv;
                    }
                const float q0 = fmaxf((float)accT[0], (float)accB[0]);
                const float q1 = fmaxf((float)accT[1], (float)accB[1]);
                ch[c] = (f16)fmaxf(fmaxf(q0, q1) + b1[c], 0.f);
            }
            f16x8 v0, v1;
            #pragma unroll
            for (int j = 0; j < 8; ++j) v0[j] = ch[j];
            v1[0] = ch[8]; v1[1] = ch[9];
            #pragma unroll
            for (int j = 2; j < 8; ++j) v1[j] = (f16)0.f;   // K-pad zeros
            unsigned char* dst = p1c + img * P1_IMG + py * P1_ROW + px * 32;
            *(f16x8*)(dst)      = v0;
            *(f16x8*)(dst + 16) = v1;
        }
    }
    __syncthreads();

    // ---------- conv2 via mfma_f32_32x32x16_f16; A-frags from global ----------
    {
        const int cy = cM >> 3, cx = cM & 7;
        const int afoff = (cM < 20 ? cM : 19) * 2 + hK;
        int bb[2];
        #pragma unroll
        for (int q = 0; q < 2; ++q) {
            const int t = wv_ * 2 + q, im = t >> 1, h2 = t & 1;
            bb[q] = im * P1_IMG + (4 * h2 + cy) * P1_ROW + cx * 32 + hK * 16;
        }
        f32x16 acc[2];
        #pragma unroll
        for (int q = 0; q < 2; ++q)
            #pragma unroll
            for (int r = 0; r < 16; ++r) acc[q][r] = 0.f;
        #pragma unroll 1
        for (int ky = 0; ky < 5; ++ky) {
            #pragma unroll
            for (int kx = 0; kx < 5; ++kx) {
                const f16x8 a = w2af[(ky * 5 + kx) * 40 + afoff];
                #pragma unroll
                for (int q = 0; q < 2; ++q) {
                    const f16x8 b =
                        *(const f16x8*)(p1c + bb[q] + ky * P1_ROW + kx * 32);
                    acc[q] = __builtin_amdgcn_mfma_f32_32x32x16_f16(a, b, acc[q],
                                                                    0, 0, 0);
                }
            }
        }
        // all waves done READING p1c before epilogue overwrites it (p2h alias)
        __syncthreads();
        // epilogue: pool via DPP (xor1 = quad_perm(1,0,3,2)=0xB1; xor8 = row_ror:8)
        #pragma unroll
        for (int q = 0; q < 2; ++q) {
            const int t = wv_ * 2 + q, im = t >> 1, h2 = t & 1;
            #pragma unroll
            for (int r = 0; r < 16; ++r) {
                const int m = (r & 3) + 8 * (r >> 2) + 4 * hK;
                float v = acc[q][r];
                v = dppmax<0xB1>(v);
                v = dppmax<0x128>(v);
                if (m < 20 && (lane & 9) == 0) {
                    const int py = 2 * h2 + (cM >> 4), px = cx >> 1;
                    p2h[im * 328 + m * 16 + py * 4 + px] =
                        (f16)fmaxf(v + b2[m], 0.f);
                }
            }
        }
    }
    __syncthreads();

    // ---------- fc1 via mfma_f32_16x16x32_f16: M=h tile/wave, N=img, K=320 ----
    {
        const int n = lane & 15, quad = lane >> 4;
        f32x4 facc = {0.f, 0.f, 0.f, 0.f};
        #pragma unroll 1
        for (int s = 0; s < 10; ++s) {
            const f16x8 a = wl1pk[(wv_ * 10 + s) * 64 + lane];  // coalesced b128
            f16x8 b = {};
            if (n < IPB)
                b = *(const f16x8*)(p2h + n * 328 + s * 32 + quad * 8);
            facc = __builtin_amdgcn_mfma_f32_16x16x32_f16(a, b, facc, 0, 0, 0);
        }
        if (n < IPB) {
            #pragma unroll
            for (int r = 0; r < 4; ++r) {
                const int h = wv_ * 16 + quad * 4 + r;
                if (h < 50)
                    h1[n * 52 + h] = fmaxf(facc[r] + bl1[h], 0.f);
            }
        }
    }
    __syncthreads();

    // ---------- fc2: 50->10 ---------------------------------------------------
    if (tid < IPB * 10) {
        const int im = tid / 10, o = tid % 10;
        const int imgo = min(blockIdx.x * IPB + im, batch - 1);
        float a = bl2[o];
        #pragma unroll
        for (int h = 0; h < 50; ++h)
            a += h1[im * 52 + h] * wl2[o * 50 + h];
        out[(size_t)imgo * 10 + o] = a;          // coalesced
    }
}

extern "C" void kernel_launch(void* const* d_in, const int* in_sizes, int n_in,
                              void* d_out, int out_size, void* d_ws, size_t ws_size,
                              hipStream_t stream) {
    const float* x   = (const float*)d_in[0];
    const float* w1  = (const float*)d_in[1];
    const float* b1  = (const float*)d_in[2];
    const float* w2  = (const float*)d_in[3];
    const float* b2  = (const float*)d_in[4];
    const float* wl1 = (const float*)d_in[5];
    const float* bl1 = (const float*)d_in[6];
    const float* wl2 = (const float*)d_in[7];
    const float* bl2 = (const float*)d_in[8];
    float* out = (float*)d_out;
    unsigned char* ws = (unsigned char*)d_ws;   // 58 KB of packed weights

    const int batch = in_sizes[0] / 784;  // 8192
    pack_weights<<<64, 256, 0, stream>>>(w1, w2, wl1, ws);
    const int grid = (batch + IPB - 1) / IPB;
    lenet_one<<<grid, THREADS, 0, stream>>>(x, ws, b1, b2, bl1, wl2, bl2,
                                            out, batch);
}